// Round 1
// baseline (1458.803 us; speedup 1.0000x reference)
//
#include <hip/hip_runtime.h>
#include <stdint.h>

#define FP8_MAX 448.0f

typedef float f32x4 __attribute__((ext_vector_type(4)));

// ---------- fp8 pack helper (HW RNE conversion, clamp to ±448 like the reference's clip) ----------
__device__ __forceinline__ unsigned int pack4_fp8(float4 v, float s) {
  float a = fminf(fmaxf(v.x * s, -FP8_MAX), FP8_MAX);
  float b = fminf(fmaxf(v.y * s, -FP8_MAX), FP8_MAX);
  float c = fminf(fmaxf(v.z * s, -FP8_MAX), FP8_MAX);
  float d = fminf(fmaxf(v.w * s, -FP8_MAX), FP8_MAX);
  unsigned int r = (unsigned int)__builtin_amdgcn_cvt_pk_fp8_f32(a, b, 0, false);
  r = (unsigned int)__builtin_amdgcn_cvt_pk_fp8_f32(c, d, (int)r, true);
  return r;
}

// ---------- async global->LDS 16B (CK-style addrspace handling) ----------
__device__ __forceinline__ void load16_to_lds(const void* g, void* l) {
  auto gp = (const __attribute__((address_space(1))) void*)(uintptr_t)g;
  auto lp = (__attribute__((address_space(3))) void*)(unsigned int)(uintptr_t)l;
  __builtin_amdgcn_global_load_lds(gp, lp, 16, 0, 0);
}

// ---------- per-tensor amax (grid-stride float4 + wave shuffle + one atomic per block) ----------
__global__ void amax_kernel(const float* __restrict__ p, int n4, unsigned int* __restrict__ slot) {
  int i = blockIdx.x * blockDim.x + threadIdx.x;
  int stride = gridDim.x * blockDim.x;
  float m = 0.0f;
  const float4* p4 = (const float4*)p;
  for (; i < n4; i += stride) {
    float4 v = p4[i];
    m = fmaxf(m, fmaxf(fmaxf(fabsf(v.x), fabsf(v.y)), fmaxf(fabsf(v.z), fabsf(v.w))));
  }
#pragma unroll
  for (int off = 32; off > 0; off >>= 1)
    m = fmaxf(m, __shfl_down(m, off, 64));
  __shared__ float wmax[4];
  int lane = threadIdx.x & 63;
  int wv = threadIdx.x >> 6;
  if (lane == 0) wmax[wv] = m;
  __syncthreads();
  if (threadIdx.x == 0) {
    m = fmaxf(fmaxf(wmax[0], wmax[1]), fmaxf(wmax[2], wmax[3]));
    atomicMax(slot, __float_as_uint(m));  // all values >=0: uint order == float order
  }
}

// ---------- quantize x: [M,K] fp32 -> [M,K] fp8 bytes ----------
__global__ void quant_x_kernel(const float* __restrict__ x, unsigned int* __restrict__ xq,
                               const unsigned int* __restrict__ hdr, int n4) {
  float s = FP8_MAX / fmaxf(__uint_as_float(hdr[0]), 1e-12f);
  int i = blockIdx.x * blockDim.x + threadIdx.x;
  int stride = gridDim.x * blockDim.x;
  const float4* x4 = (const float4*)x;
  for (; i < n4; i += stride)
    xq[i] = pack4_fp8(x4[i], s);
}

// ---------- quantize + transpose weight: [K,N] fp32 -> [N,K] fp8 bytes (64x64 LDS tile) ----------
__global__ void quant_w_t_kernel(const float* __restrict__ w, unsigned char* __restrict__ wqT,
                                 const unsigned int* __restrict__ hdr, int K, int N) {
  __shared__ unsigned char tile[64][68];  // +4 pad: stride 17 words, conflict-free columns
  float s = FP8_MAX / fmaxf(__uint_as_float(hdr[1]), 1e-12f);
  int tk0 = blockIdx.y << 6;
  int tn0 = blockIdx.x << 6;
  int t = threadIdx.x;
  int r = t >> 2;            // 0..63 (k row within tile)
  int c0 = (t & 3) << 4;     // 0,16,32,48 (n col chunk)
  const float4* src = (const float4*)(w + (size_t)(tk0 + r) * N + tn0 + c0);
#pragma unroll
  for (int i = 0; i < 4; ++i) {
    unsigned int pk = pack4_fp8(src[i], s);
    *(unsigned int*)&tile[r][c0 + i * 4] = pk;  // row stride 68 is 4B-aligned
  }
  __syncthreads();
  int n = t >> 2;            // output row (n)
  int kc = (t & 3) << 4;     // k chunk
  unsigned int wds[4];
#pragma unroll
  for (int i = 0; i < 4; ++i) {
    wds[i] = (unsigned int)tile[kc + i * 4 + 0][n]
           | ((unsigned int)tile[kc + i * 4 + 1][n] << 8)
           | ((unsigned int)tile[kc + i * 4 + 2][n] << 16)
           | ((unsigned int)tile[kc + i * 4 + 3][n] << 24);
  }
  *(uint4*)(wqT + (size_t)(tn0 + n) * K + tk0 + kc) = make_uint4(wds[0], wds[1], wds[2], wds[3]);
}

// ---------- fp8 GEMM: out[M,N] = (xq @ wqT^T) * scale ----------
// m97 structure: 128x128 tile, BK=64, 4 waves, 4x4 16x16x32 fp8 MFMA per wave,
// global_load_lds width-16 staging, 2-barrier K-loop.
__global__ __launch_bounds__(256) void gemm_fp8_kernel(
    const unsigned char* __restrict__ Aq,   // [M,K] fp8
    const unsigned char* __restrict__ Bq,   // [N,K] fp8 (w transposed)
    const unsigned int* __restrict__ hdr,
    float* __restrict__ out, int M, int N, int K) {
  __shared__ __align__(16) unsigned char As[128 * 64];
  __shared__ __align__(16) unsigned char Bs[128 * 64];

  const int t = threadIdx.x;
  const int wave = t >> 6;
  const int lane = t & 63;
  const int row16 = lane & 15;
  const int quad = lane >> 4;
  const int m0 = blockIdx.y << 7;
  const int n0 = blockIdx.x << 7;
  const int waveM = (wave >> 1) << 6;
  const int waveN = (wave & 1) << 6;

  // staging: per wave 1KiB chunks; LDS layout [row][k] with 64B rows, no pad
  // (global_load_lds dest is wave-uniform base + lane*16 — layout must match lane order)
  const int ldsIdx = wave * 1024 + lane * 16;
  const int sRow = ldsIdx >> 6;        // wave*16 + lane/4
  const int sCol = ldsIdx & 63;        // (lane%4)*16

  const unsigned char* ag0 = Aq + (size_t)(m0 + sRow) * K + sCol;
  const unsigned char* ag1 = Aq + (size_t)(m0 + sRow + 64) * K + sCol;
  const unsigned char* bg0 = Bq + (size_t)(n0 + sRow) * K + sCol;
  const unsigned char* bg1 = Bq + (size_t)(n0 + sRow + 64) * K + sCol;

  unsigned char* al0 = &As[ldsIdx];
  unsigned char* al1 = &As[ldsIdx + 4096];
  unsigned char* bl0 = &Bs[ldsIdx];
  unsigned char* bl1 = &Bs[ldsIdx + 4096];

  f32x4 acc[4][4] = {};

  for (int k0 = 0; k0 < K; k0 += 64) {
    load16_to_lds(ag0 + k0, al0);
    load16_to_lds(ag1 + k0, al1);
    load16_to_lds(bg0 + k0, bl0);
    load16_to_lds(bg1 + k0, bl1);
    __syncthreads();  // drains vmcnt then barrier -> tiles ready
#pragma unroll
    for (int kk = 0; kk < 64; kk += 32) {
      long af[4], bf[4];
#pragma unroll
      for (int mi = 0; mi < 4; ++mi)
        af[mi] = *(const long*)(As + (waveM + mi * 16 + row16) * 64 + kk + quad * 8);
#pragma unroll
      for (int ni = 0; ni < 4; ++ni)
        bf[ni] = *(const long*)(Bs + (waveN + ni * 16 + row16) * 64 + kk + quad * 8);
#pragma unroll
      for (int mi = 0; mi < 4; ++mi)
#pragma unroll
        for (int ni = 0; ni < 4; ++ni)
          acc[mi][ni] = __builtin_amdgcn_mfma_f32_16x16x32_fp8_fp8(af[mi], bf[ni], acc[mi][ni], 0, 0, 0);
    }
    __syncthreads();  // all reads done before next overwrite
  }

  // epilogue: dequant scale = (amax_x/448)*(amax_w/448)
  const float ax = fmaxf(__uint_as_float(hdr[0]), 1e-12f);
  const float aw = fmaxf(__uint_as_float(hdr[1]), 1e-12f);
  const float sc = (ax / FP8_MAX) * (aw / FP8_MAX);
#pragma unroll
  for (int mi = 0; mi < 4; ++mi) {
#pragma unroll
    for (int ni = 0; ni < 4; ++ni) {
      const int gc = n0 + waveN + ni * 16 + row16;
#pragma unroll
      for (int r = 0; r < 4; ++r) {
        const int gr = m0 + waveM + mi * 16 + quad * 4 + r;
        out[(size_t)gr * N + gc] = acc[mi][ni][r] * sc;  // C/D: col=lane&15, row=quad*4+reg
      }
    }
  }
}

extern "C" void kernel_launch(void* const* d_in, const int* in_sizes, int n_in,
                              void* d_out, int out_size, void* d_ws, size_t ws_size,
                              hipStream_t stream) {
  const float* x = (const float*)d_in[0];       // [M,K] fp32 (flattened [8,2048,4096])
  const float* w = (const float*)d_in[1];       // [K,N] fp32
  float* out = (float*)d_out;

  const int K = 4096;
  const int N = 4096;
  const int M = in_sizes[0] / K;                // 16384

  // workspace layout: [0..16) amax slots (uint bits), then xq [M*K], then wqT [N*K]
  unsigned int* hdr = (unsigned int*)d_ws;
  unsigned char* xq = (unsigned char*)d_ws + 16;
  unsigned char* wqT = xq + (size_t)M * K;

  hipMemsetAsync(d_ws, 0, 16, stream);  // zero amax slots (ws is poisoned each call)

  amax_kernel<<<2048, 256, 0, stream>>>(x, (int)((size_t)M * K / 4), hdr + 0);
  amax_kernel<<<1024, 256, 0, stream>>>(w, (int)((size_t)K * N / 4), hdr + 1);

  quant_x_kernel<<<4096, 256, 0, stream>>>(x, (unsigned int*)xq, hdr, (int)((size_t)M * K / 4));
  quant_w_t_kernel<<<dim3(N / 64, K / 64), 256, 0, stream>>>(w, wqT, hdr, K, N);

  gemm_fp8_kernel<<<dim3(N / 128, M / 128), 256, 0, stream>>>(xq, wqT, hdr, out, M, N, K);
}

// Round 2
// 1137.441 us; speedup vs baseline: 1.2825x; 1.2825x over previous
//
#include <hip/hip_runtime.h>
#include <stdint.h>

#define FP8_MAX 448.0f

typedef float f32x4 __attribute__((ext_vector_type(4)));

// ---------- fp8 pack helper (HW RNE conversion, clamp to ±448 like the reference's clip) ----------
__device__ __forceinline__ unsigned int pack4_fp8(float4 v, float s) {
  float a = fminf(fmaxf(v.x * s, -FP8_MAX), FP8_MAX);
  float b = fminf(fmaxf(v.y * s, -FP8_MAX), FP8_MAX);
  float c = fminf(fmaxf(v.z * s, -FP8_MAX), FP8_MAX);
  float d = fminf(fmaxf(v.w * s, -FP8_MAX), FP8_MAX);
  unsigned int r = (unsigned int)__builtin_amdgcn_cvt_pk_fp8_f32(a, b, 0, false);
  r = (unsigned int)__builtin_amdgcn_cvt_pk_fp8_f32(c, d, (int)r, true);
  return r;
}

// ---------- async global->LDS 16B ----------
__device__ __forceinline__ void load16_to_lds(const void* g, void* l) {
  auto gp = (const __attribute__((address_space(1))) void*)(uintptr_t)g;
  auto lp = (__attribute__((address_space(3))) void*)(unsigned int)(uintptr_t)l;
  __builtin_amdgcn_global_load_lds(gp, lp, 16, 0, 0);
}

// ---------- per-tensor amax (grid-stride float4 + wave shuffle + one atomic per block) ----------
__global__ void amax_kernel(const float* __restrict__ p, int n4, unsigned int* __restrict__ slot) {
  int i = blockIdx.x * blockDim.x + threadIdx.x;
  int stride = gridDim.x * blockDim.x;
  float m = 0.0f;
  const float4* p4 = (const float4*)p;
  for (; i < n4; i += stride) {
    float4 v = p4[i];
    m = fmaxf(m, fmaxf(fmaxf(fabsf(v.x), fabsf(v.y)), fmaxf(fabsf(v.z), fabsf(v.w))));
  }
#pragma unroll
  for (int off = 32; off > 0; off >>= 1)
    m = fmaxf(m, __shfl_down(m, off, 64));
  __shared__ float wmax[4];
  int lane = threadIdx.x & 63;
  int wv = threadIdx.x >> 6;
  if (lane == 0) wmax[wv] = m;
  __syncthreads();
  if (threadIdx.x == 0) {
    m = fmaxf(fmaxf(wmax[0], wmax[1]), fmaxf(wmax[2], wmax[3]));
    atomicMax(slot, __float_as_uint(m));  // all values >=0: uint order == float order
  }
}

// ---------- quantize x: [M,K] fp32 -> [M,K] fp8 bytes ----------
__global__ void quant_x_kernel(const float* __restrict__ x, unsigned int* __restrict__ xq,
                               const unsigned int* __restrict__ hdr, int n4) {
  float s = FP8_MAX / fmaxf(__uint_as_float(hdr[0]), 1e-12f);
  int i = blockIdx.x * blockDim.x + threadIdx.x;
  int stride = gridDim.x * blockDim.x;
  const float4* x4 = (const float4*)x;
  for (; i < n4; i += stride)
    xq[i] = pack4_fp8(x4[i], s);
}

// ---------- quantize + transpose weight: [K,N] fp32 -> [N,K] fp8 bytes ----------
// Register-level 4x4 byte transpose; LDS word-granular both directions (no ds_read_u8).
__global__ void quant_w_t_kernel(const float* __restrict__ w, unsigned char* __restrict__ wqT,
                                 const unsigned int* __restrict__ hdr, int K, int N) {
  __shared__ unsigned int tileT[64][17];  // [n][k-word], +1 word pad
  float s = FP8_MAX / fmaxf(__uint_as_float(hdr[1]), 1e-12f);
  int tk0 = blockIdx.y << 6;
  int tn0 = blockIdx.x << 6;
  int t = threadIdx.x;

  // phase 1: read 4(k) x 4(n) fp32 block, quantize, transpose bytes in registers
  int rn = (t & 15) << 2;   // n within tile; adjacent lanes -> adjacent 16B => coalesced reads
  int rk = (t >> 4) << 2;   // k within tile
  unsigned int wrow[4];
#pragma unroll
  for (int j = 0; j < 4; ++j) {
    float4 v = *(const float4*)(w + (size_t)(tk0 + rk + j) * N + tn0 + rn);
    wrow[j] = pack4_fp8(v, s);  // bytes = cols n..n+3 of row k+j
  }
#pragma unroll
  for (int i = 0; i < 4; ++i) {
    unsigned int colw = ((wrow[0] >> (8 * i)) & 0xffu)
                      | (((wrow[1] >> (8 * i)) & 0xffu) << 8)
                      | (((wrow[2] >> (8 * i)) & 0xffu) << 16)
                      | (((wrow[3] >> (8 * i)) & 0xffu) << 24);
    tileT[rn + i][rk >> 2] = colw;  // bytes = rows k..k+3 of col n+i
  }
  __syncthreads();

  // phase 2: 16B per thread, coalesced store of wqT rows
  int n = t >> 2;
  int kc = (t & 3) << 2;  // word index within row
  uint4 v = make_uint4(tileT[n][kc], tileT[n][kc + 1], tileT[n][kc + 2], tileT[n][kc + 3]);
  *(uint4*)(wqT + (size_t)(tn0 + n) * K + tk0 + (kc << 2)) = v;
}

// ---------- fp8 GEMM: out[M,N] = (xq @ wqT^T) * scale ----------
// m97 structure: 128x128 tile, BK=64, 4 waves, 4x4 16x16x32 fp8 MFMA per wave,
// global_load_lds width-16 staging, 2-barrier K-loop.
// LDS layout XOR-swizzled: physical 16B chunk p of row r holds logical chunk p^(r&3),
// making the ds_read_b64 fragment loads bank-conflict-free (4 lanes per bank-pair).
__global__ __launch_bounds__(256) void gemm_fp8_kernel(
    const unsigned char* __restrict__ Aq,   // [M,K] fp8
    const unsigned char* __restrict__ Bq,   // [N,K] fp8 (w transposed)
    const unsigned int* __restrict__ hdr,
    float* __restrict__ out, int M, int N, int K) {
  __shared__ __align__(16) unsigned char As[128 * 64];
  __shared__ __align__(16) unsigned char Bs[128 * 64];

  const int t = threadIdx.x;
  const int wave = t >> 6;
  const int lane = t & 63;
  const int row16 = lane & 15;
  const int quad = lane >> 4;
  const int m0 = blockIdx.y << 7;
  const int n0 = blockIdx.x << 7;
  const int waveM = (wave >> 1) << 6;
  const int waveN = (wave & 1) << 6;

  // staging: LDS dest is lane-contiguous (global_load_lds requirement);
  // global source column is swizzled so LDS[r][p] = A[r][(p^(r&3))*16..]
  const int ldsIdx = wave * 1024 + lane * 16;
  const int sRow = wave * 16 + (lane >> 2);
  const int sCol = (((lane & 3) ^ (sRow & 3)) << 4);

  const unsigned char* ag0 = Aq + (size_t)(m0 + sRow) * K + sCol;
  const unsigned char* ag1 = Aq + (size_t)(m0 + sRow + 64) * K + sCol;
  const unsigned char* bg0 = Bq + (size_t)(n0 + sRow) * K + sCol;
  const unsigned char* bg1 = Bq + (size_t)(n0 + sRow + 64) * K + sCol;

  unsigned char* al0 = &As[ldsIdx];
  unsigned char* al1 = &As[ldsIdx + 4096];
  unsigned char* bl0 = &Bs[ldsIdx];
  unsigned char* bl1 = &Bs[ldsIdx + 4096];

  const int sw = row16 & 3;  // fragment-read swizzle key (row & 3 of the tile row)

  f32x4 acc[4][4] = {};

  for (int k0 = 0; k0 < K; k0 += 64) {
    load16_to_lds(ag0 + k0, al0);
    load16_to_lds(ag1 + k0, al1);
    load16_to_lds(bg0 + k0, bl0);
    load16_to_lds(bg1 + k0, bl1);
    __syncthreads();
#pragma unroll
    for (int kk = 0; kk < 64; kk += 32) {
      // logical 16B chunk = (kk>>4)+(quad>>1); physical = logical ^ sw; +8B if quad odd
      const int colOff = ((((kk >> 4) + (quad >> 1)) ^ sw) << 4) + ((quad & 1) << 3);
      long af[4], bf[4];
#pragma unroll
      for (int mi = 0; mi < 4; ++mi)
        af[mi] = *(const long*)(As + (waveM + mi * 16 + row16) * 64 + colOff);
#pragma unroll
      for (int ni = 0; ni < 4; ++ni)
        bf[ni] = *(const long*)(Bs + (waveN + ni * 16 + row16) * 64 + colOff);
#pragma unroll
      for (int mi = 0; mi < 4; ++mi)
#pragma unroll
        for (int ni = 0; ni < 4; ++ni)
          acc[mi][ni] = __builtin_amdgcn_mfma_f32_16x16x32_fp8_fp8(af[mi], bf[ni], acc[mi][ni], 0, 0, 0);
    }
    __syncthreads();
  }

  // epilogue: dequant scale = (amax_x/448)*(amax_w/448)
  const float ax = fmaxf(__uint_as_float(hdr[0]), 1e-12f);
  const float aw = fmaxf(__uint_as_float(hdr[1]), 1e-12f);
  const float sc = (ax / FP8_MAX) * (aw / FP8_MAX);
#pragma unroll
  for (int mi = 0; mi < 4; ++mi) {
#pragma unroll
    for (int ni = 0; ni < 4; ++ni) {
      const int gc = n0 + waveN + ni * 16 + row16;
#pragma unroll
      for (int r = 0; r < 4; ++r) {
        const int gr = m0 + waveM + mi * 16 + quad * 4 + r;
        out[(size_t)gr * N + gc] = acc[mi][ni][r] * sc;  // C/D: col=lane&15, row=quad*4+reg
      }
    }
  }
}

extern "C" void kernel_launch(void* const* d_in, const int* in_sizes, int n_in,
                              void* d_out, int out_size, void* d_ws, size_t ws_size,
                              hipStream_t stream) {
  const float* x = (const float*)d_in[0];       // [M,K] fp32 (flattened [8,2048,4096])
  const float* w = (const float*)d_in[1];       // [K,N] fp32
  float* out = (float*)d_out;

  const int K = 4096;
  const int N = 4096;
  const int M = in_sizes[0] / K;                // 16384

  // workspace layout: [0..16) amax slots (uint bits), then xq [M*K], then wqT [N*K]
  unsigned int* hdr = (unsigned int*)d_ws;
  unsigned char* xq = (unsigned char*)d_ws + 16;
  unsigned char* wqT = xq + (size_t)M * K;

  hipMemsetAsync(d_ws, 0, 16, stream);  // zero amax slots (ws is poisoned each call)

  amax_kernel<<<2048, 256, 0, stream>>>(x, (int)((size_t)M * K / 4), hdr + 0);
  amax_kernel<<<1024, 256, 0, stream>>>(w, (int)((size_t)K * N / 4), hdr + 1);

  quant_x_kernel<<<4096, 256, 0, stream>>>(x, (unsigned int*)xq, hdr, (int)((size_t)M * K / 4));
  quant_w_t_kernel<<<dim3(N / 64, K / 64), 256, 0, stream>>>(w, wqT, hdr, K, N);

  gemm_fp8_kernel<<<dim3(N / 128, M / 128), 256, 0, stream>>>(xq, wqT, hdr, out, M, N, K);
}